// Round 7
// baseline (614.916 us; speedup 1.0000x reference)
//
#include <hip/hip_runtime.h>
#include <math.h>

#define WAVE 64
#define NC 21

__device__ __forceinline__ unsigned f32_ord(float f) {
    unsigned u = __float_as_uint(f);
    return (u & 0x80000000u) ? ~u : (u | 0x80000000u);
}

__device__ __forceinline__ float wave_max_f32(float v) {
#pragma unroll
    for (int off = 32; off >= 1; off >>= 1)
        v = fmaxf(v, __shfl_xor(v, off, WAVE));
    return v;
}

__device__ __forceinline__ float wave_sum_f32(float v) {
#pragma unroll
    for (int off = 32; off >= 1; off >>= 1)
        v += __shfl_xor(v, off, WAVE);
    return v;
}

// Full bitonic sort of 64 u64 keys (one per lane), ascending across lanes.
__device__ __forceinline__ unsigned long long bitonic_sort64(
    unsigned long long v, int lane)
{
#pragma unroll
    for (int k = 2; k <= 64; k <<= 1) {
#pragma unroll
        for (int j = k >> 1; j > 0; j >>= 1) {
            unsigned long long o = __shfl_xor(v, j, WAVE);
            bool take_min = (((lane & j) == 0) == ((lane & k) == 0));
            unsigned long long mn = (v < o) ? v : o;
            unsigned long long mx = (v < o) ? o : v;
            v = take_min ? mn : mx;
        }
    }
    return v;
}

// h sorted asc, c sorted asc -> sorted asc smallest-64 of the union.
__device__ __forceinline__ unsigned long long bitonic_merge_keep_low(
    unsigned long long h, unsigned long long c, int lane)
{
    unsigned long long cr = __shfl(c, 63 - lane, WAVE);   // reverse c
    unsigned long long v = (h < cr) ? h : cr;             // low half, bitonic
#pragma unroll
    for (int j = 32; j > 0; j >>= 1) {                    // clean ascending
        unsigned long long o = __shfl_xor(v, j, WAVE);
        bool take_min = ((lane & j) == 0);
        unsigned long long mn = (v < o) ? v : o;
        unsigned long long mx = (v < o) ? o : v;
        v = take_min ? mn : mx;
    }
    return v;
}

// ---------------------------------------------------------------------------
// Wave-local exact top-NS of NI candidates. Returns packed (key<<32|idx);
// lane l < NS holds the (l+1)-th nearest (u64 ascending == (dist, idx)
// ascending == jax.lax.top_k order incl. tie-break). No LDS, no barriers.
// Skipping is exact: u64 keys are distinct, so any candidate >= current
// h[NS-1] can never enter the true top-NS.
// ---------------------------------------------------------------------------
template <int NI, int NS>
__device__ __forceinline__ unsigned long long wave_topk(
    const float* __restrict__ rp,   // [NI,3] coords for this batch
    float qx, float qy, float qz, float nq, int lane)
{
    constexpr int NCH = (NI + 63) / 64;

    unsigned long long h;
    {
        unsigned long long p = ~0ull;
        if (NI >= 64 || lane < NI) {
            int g = lane;
            float rx = rp[3*g], ry = rp[3*g+1], rz = rp[3*g+2];
            float nr = rx*rx + ry*ry + rz*rz;
            float dot = qx*rx + qy*ry + qz*rz;
            unsigned o = f32_ord(-2.0f*dot + nq + nr);  // identical expr R1-R6
            p = ((unsigned long long)o << 32) | (unsigned)g;
        }
        h = bitonic_sort64(p, lane);
    }
    if (NCH > 1) {
        unsigned long long tau = __shfl(h, NS - 1, WAVE);
#pragma unroll 1
        for (int cch = 1; cch < NCH; ++cch) {
            int g = cch * 64 + lane;
            float rx = rp[3*g], ry = rp[3*g+1], rz = rp[3*g+2];
            float nr = rx*rx + ry*ry + rz*rz;
            float dot = qx*rx + qy*ry + qz*rz;
            unsigned o = f32_ord(-2.0f*dot + nq + nr);
            unsigned long long p = ((unsigned long long)o << 32) | (unsigned)g;
            if (__ballot(p < tau) == 0ull) continue;     // wave-uniform skip
            unsigned long long cs = bitonic_sort64(p, lane);
            h = bitonic_merge_keep_low(h, cs, lane);
            tau = __shfl(h, NS - 1, WAVE);
        }
    }
    return h;
}

// ---------------------------------------------------------------------------
template <int NQ, int K>
__device__ __forceinline__ void knn_level(
    const float* __restrict__ qc, const float* __restrict__ rc,
    const int* __restrict__ rl, int* __restrict__ out, int q, int lane)
{
    int b = q / NQ, qi = q - b * NQ;
    const float* qp = qc + ((long)b * NQ + qi) * 3;
    float qx = qp[0], qy = qp[1], qz = qp[2];
    float nq = qx*qx + qy*qy + qz*qz;
    unsigned long long h =
        wave_topk<4096, K>(rc + (long)b * 4096 * 3, qx, qy, qz, nq, lane);
    int nb = (int)(unsigned)h;
    int lb = (lane < K) ? rl[(long)b * 4096 + nb] : -1;
    int cnt = 0;
#pragma unroll
    for (int k = 0; k < K; ++k) {
        int lk = __shfl(lb, k, WAVE);
        cnt += (lk == lane) ? 1 : 0;
    }
    int key = (lane < NC) ? ((cnt << 8) | (255 - lane)) : 0;
#pragma unroll
    for (int off = 32; off >= 1; off >>= 1) {
        int o = __shfl_xor(key, off, WAVE);
        key = (o > key) ? o : key;
    }
    if (lane == 0) out[(long)b * NQ + qi] = 255 - (key & 255);
}

template <int NI, int NS>
__device__ __forceinline__ void boundary_level(
    const float* __restrict__ coord, const float* __restrict__ feat,
    const int* __restrict__ lbl,
    double* __restrict__ pos, double* __restrict__ neg, int* __restrict__ anyf,
    int q, int lane)
{
    int b = q / NI, qi = q - b * NI;
    const float* qp = coord + ((long)b * NI + qi) * 3;
    float qx = qp[0], qy = qp[1], qz = qp[2];
    float nq = qx*qx + qy*qy + qz*qz;
    unsigned long long h =
        wave_topk<NI, NS>(coord + (long)b * NI * 3, qx, qy, qz, nq, lane);
    int nb = (int)(unsigned)h;
    int center = lbl[(long)b * NI + qi];
    bool m = false;
    float dj = -INFINITY;
    if (lane < NS) {
        m = (lbl[(long)b * NI + nb] == center);
        const float4* fq = (const float4*)(feat + ((long)b * NI + qi) * 32);
        const float4* fn = (const float4*)(feat + ((long)b * NI + nb) * 32);
        float s = 0.f;
#pragma unroll
        for (int d = 0; d < 8; ++d) {
            float4 a = fq[d], c = fn[d];
            float d0 = a.x - c.x, d1 = a.y - c.y;
            float d2 = a.z - c.z, d3 = a.w - c.w;
            s += d0*d0 + d1*d1 + d2*d2 + d3*d3;
        }
        dj = -sqrtf(s + 1e-6f);
    }
    unsigned long long mb = __ballot(m);
    int cnt = __popcll(mb);
    float mxv = wave_max_f32(dj);          // lanes >= NS hold -inf
    float ej = 0.f, pj = 0.f;
    if (lane < NS) {
        ej = expf(dj - mxv);               // TEMPERATURE == 1
        pj = m ? ej : 0.f;
    }
    float se = wave_sum_f32(ej);
    float sp = wave_sum_f32(pj);
    bool pm = (cnt > 0) && (cnt < NS);
    if (pm && lane == 0) {
        atomicAdd(pos, (double)sp);
        atomicAdd(neg, (double)se);
        *anyf = 1;
    }
}

// ---------------------------------------------------------------------------
// 256 threads = 4 independent waves, one query each. No barriers, no LDS.
// ---------------------------------------------------------------------------
__global__ __launch_bounds__(256) void knn_fused(
    const float* __restrict__ c1, const float* __restrict__ c2,
    const float* __restrict__ c3, const float* __restrict__ c4,
    const float* __restrict__ c0, const int* __restrict__ labels,
    int* __restrict__ lbl1, int* __restrict__ lbl2,
    int* __restrict__ lbl3, int* __restrict__ lbl4,
    double* __restrict__ posA, double* __restrict__ negA,
    int* __restrict__ anyA, int B)
{
    int q = blockIdx.x * 4 + (threadIdx.x >> 6);
    int lane = threadIdx.x & 63;
    int n1 = B * 1024, n2 = n1 + B * 256, n3 = n2 + B * 64, n4 = n3 + B * 16;
    if (q < n1)      knn_level<1024, 4>(c1, c0, labels, lbl1, q,      lane);
    else if (q < n2) knn_level<256,  8>(c2, c0, labels, lbl2, q - n1, lane);
    else if (q < n3) knn_level<64,  12>(c3, c0, labels, lbl3, q - n2, lane);
    else if (q < n4) knn_level<16,  16>(c4, c0, labels, lbl4, q - n3, lane);
    else if (threadIdx.x < 5) {
        posA[threadIdx.x] = 0.0; negA[threadIdx.x] = 0.0; anyA[threadIdx.x] = 0;
    }
}

__global__ __launch_bounds__(256) void boundary_fused(
    const float* __restrict__ c0, const float* __restrict__ c1,
    const float* __restrict__ c2, const float* __restrict__ c3,
    const float* __restrict__ c4,
    const float* __restrict__ f0, const float* __restrict__ f1,
    const float* __restrict__ f2, const float* __restrict__ f3,
    const float* __restrict__ f4,
    const int* __restrict__ labels, const int* __restrict__ lbl1,
    const int* __restrict__ lbl2, const int* __restrict__ lbl3,
    const int* __restrict__ lbl4,
    double* __restrict__ posA, double* __restrict__ negA,
    int* __restrict__ anyA, int B)
{
    int q = blockIdx.x * 4 + (threadIdx.x >> 6);
    int lane = threadIdx.x & 63;
    int m0 = B * 4096, m1 = m0 + B * 1024, m2 = m1 + B * 256;
    int m3 = m2 + B * 64, m4 = m3 + B * 16;
    if (q < m0)
        boundary_level<4096, 64>(c0, f0, labels, posA+0, negA+0, anyA+0, q,      lane);
    else if (q < m1)
        boundary_level<1024, 32>(c1, f1, lbl1,   posA+1, negA+1, anyA+1, q - m0, lane);
    else if (q < m2)
        boundary_level<256,  16>(c2, f2, lbl2,   posA+2, negA+2, anyA+2, q - m1, lane);
    else if (q < m3)
        boundary_level<64,    8>(c3, f3, lbl3,   posA+3, negA+3, anyA+3, q - m2, lane);
    else if (q < m4)
        boundary_level<16,    4>(c4, f4, lbl4,   posA+4, negA+4, anyA+4, q - m3, lane);
}

__global__ void finalize_kernel(const double* __restrict__ pos,
                                const double* __restrict__ neg,
                                const int* __restrict__ anyf,
                                float* __restrict__ out) {
    if (threadIdx.x == 0 && blockIdx.x == 0) {
        float loss = 0.f;
        for (int i = 0; i < 5; ++i) {
            if (anyf[i]) {
                float p = (float)pos[i];
                float n = (float)neg[i];
                loss += -logf(p / (n + 1e-6f));
            }
        }
        out[0] = loss;
    }
}

extern "C" void kernel_launch(void* const* d_in, const int* in_sizes, int n_in,
                              void* d_out, int out_size, void* d_ws, size_t ws_size,
                              hipStream_t stream) {
    (void)out_size; (void)ws_size;
    const int* labels = (const int*)d_in[0];
    const float* coord[5];
    const float* feat[5];
    bool interleaved = (n_in >= 3 && in_sizes[2] == 2 * 4096 * 32);
    if (interleaved) {
        for (int i = 0; i < 5; ++i) {
            coord[i] = (const float*)d_in[1 + 2 * i];
            feat[i]  = (const float*)d_in[2 + 2 * i];
        }
    } else {
        for (int i = 0; i < 5; ++i) {
            coord[i] = (const float*)d_in[1 + i];
            feat[i]  = (const float*)d_in[6 + i];
        }
    }
    int B = in_sizes[0] / 4096;   // = 2

    double* posA = (double*)d_ws;            // 5 doubles
    double* negA = posA + 5;                 // 5 doubles
    int* anyA = (int*)(negA + 5);            // 5 ints (+3 pad)
    int* lbl1 = anyA + 8;
    int* lbl2 = lbl1 + B * 1024;
    int* lbl3 = lbl2 + B * 256;
    int* lbl4 = lbl3 + B * 64;

    int n4 = B * (1024 + 256 + 64 + 16);
    int knn_grid = (n4 + 3) / 4 + 1;                   // +1 block does init
    hipLaunchKernelGGL(knn_fused, dim3(knn_grid), dim3(256), 0, stream,
                       coord[1], coord[2], coord[3], coord[4],
                       coord[0], labels, lbl1, lbl2, lbl3, lbl4,
                       posA, negA, anyA, B);

    int m4 = B * (4096 + 1024 + 256 + 64 + 16);
    int bnd_grid = (m4 + 3) / 4;
    hipLaunchKernelGGL(boundary_fused, dim3(bnd_grid), dim3(256), 0, stream,
                       coord[0], coord[1], coord[2], coord[3], coord[4],
                       feat[0], feat[1], feat[2], feat[3], feat[4],
                       labels, lbl1, lbl2, lbl3, lbl4,
                       posA, negA, anyA, B);

    hipLaunchKernelGGL(finalize_kernel, dim3(1), dim3(1), 0, stream,
                       posA, negA, anyA, (float*)d_out);
}

// Round 9
// 401.284 us; speedup vs baseline: 1.5324x; 1.5324x over previous
//
#include <hip/hip_runtime.h>
#include <math.h>

#define WAVE 64
#define NC 21

__device__ __forceinline__ unsigned f32_ord(float f) {
    unsigned u = __float_as_uint(f);
    return (u & 0x80000000u) ? ~u : (u | 0x80000000u);
}

__device__ __forceinline__ int wave_sum_i32(int v) {
#pragma unroll
    for (int off = 32; off >= 1; off >>= 1)
        v += __shfl_xor(v, off, WAVE);
    return v;
}

__device__ __forceinline__ unsigned wave_min_u32(unsigned v) {
#pragma unroll
    for (int off = 32; off >= 1; off >>= 1) {
        unsigned o = (unsigned)__shfl_xor((int)v, off, WAVE);
        v = (o < v) ? o : v;
    }
    return v;
}

__device__ __forceinline__ unsigned wave_max_u32(unsigned v) {
#pragma unroll
    for (int off = 32; off >= 1; off >>= 1) {
        unsigned o = (unsigned)__shfl_xor((int)v, off, WAVE);
        v = (o > v) ? o : v;
    }
    return v;
}

__device__ __forceinline__ unsigned long long wave_min_u64(unsigned long long v) {
#pragma unroll
    for (int off = 32; off >= 1; off >>= 1) {
        unsigned long long o = __shfl_xor(v, off, WAVE);
        v = (o < v) ? o : v;
    }
    return v;
}

__device__ __forceinline__ float wave_max_f32(float v) {
#pragma unroll
    for (int off = 32; off >= 1; off >>= 1)
        v = fmaxf(v, __shfl_xor(v, off, WAVE));
    return v;
}

__device__ __forceinline__ float wave_sum_f32(float v) {
#pragma unroll
    for (int off = 32; off >= 1; off >>= 1)
        v += __shfl_xor(v, off, WAVE);
    return v;
}

// Full bitonic sort of 64 u64 keys (one per lane), ascending across lanes.
// (verified exact in R7, absmax 0)
__device__ __forceinline__ unsigned long long bitonic_sort64(
    unsigned long long v, int lane)
{
#pragma unroll
    for (int k = 2; k <= 64; k <<= 1) {
#pragma unroll
        for (int j = k >> 1; j > 0; j >>= 1) {
            unsigned long long o = __shfl_xor(v, j, WAVE);
            bool take_min = (((lane & j) == 0) == ((lane & k) == 0));
            unsigned long long mn = (v < o) ? v : o;
            unsigned long long mx = (v < o) ? o : v;
            v = take_min ? mn : mx;
        }
    }
    return v;
}

struct SelShm {
    unsigned long long cbuf[64];   // boundary-band candidates (key<<32|idx)
    unsigned long long mw[4];      // per-wave u64 minima (rare path)
    int sel[64];                   // selected global indices
    int swv[4][4];                 // rotating count slots [it&3][wid]
    unsigned smin[4], smax[4];
    int scnt, bcnt;
};

// ---------------------------------------------------------------------------
// Block-wide exact top-NS set selection. 256 threads, thread t owns keys
// g = j*256+t. Result: shm.sel[0..NS) = selected global indices (set order).
// Tie-break identical to jax.lax.top_k (u64 (key,idx) order).
// Adaptive value-bisection: exit when boundary band <= CAP, resolve band
// with one 64-lane u64 bitonic sort.
// ---------------------------------------------------------------------------
template <int NI, int NS>
__device__ __forceinline__ void block_topNS(
    const float4* __restrict__ pts,   // [NI] packed (x,y,z,|r|^2), this batch
    float qx, float qy, float qz, float nq,
    SelShm& shm, int tid)
{
    constexpr int NPL = (NI + 255) / 256;
    constexpr bool FULL = (NPL * 256 == NI);
    constexpr int CAP = 48;
    const int lane = tid & 63;
    const int wid = tid >> 6;
    const unsigned long long lmask = (1ull << lane) - 1ull;

    unsigned ok[NPL];
#pragma unroll
    for (int j = 0; j < NPL; ++j) {
        int g = j * 256 + tid;
        unsigned o = 0xFFFFFFFFu;
        if (FULL || g < NI) {
            float4 p = pts[g];
            float dot = qx * p.x + qy * p.y + qz * p.z;
            o = f32_ord(-2.0f * dot + nq + p.w);   // identical expr R1-R7
        }
        ok[j] = o;
    }

    // block min/max seed
    unsigned mn = 0xFFFFFFFFu, mx = 0u;
#pragma unroll
    for (int j = 0; j < NPL; ++j) {
        mn = (ok[j] < mn) ? ok[j] : mn;
        unsigned v = (ok[j] == 0xFFFFFFFFu) ? 0u : ok[j];
        mx = (v > mx) ? v : mx;
    }
    mn = wave_min_u32(mn);
    mx = wave_max_u32(mx);
    if (lane == 0) { shm.smin[wid] = mn; shm.smax[wid] = mx; }
    if (tid == 0)  { shm.scnt = 0; shm.bcnt = 0; }
    __syncthreads();
#pragma unroll
    for (int w = 0; w < 4; ++w) {
        unsigned a = shm.smin[w], b = shm.smax[w];
        mn = (a < mn) ? a : mn;
        mx = (b > mx) ? b : mx;
    }

    unsigned lo = mn, hi = mx;
    int cLo = 0, cHi = NI;     // count(<lo), count(<=hi)  (valid keys only)
    int it = 0;
    while (lo < hi && (cHi - cLo) > CAP) {
        unsigned piv = lo + ((hi - lo) >> 1);
        int c = 0;
#pragma unroll
        for (int j = 0; j < NPL; ++j) c += (ok[j] <= piv) ? 1 : 0;
        c = wave_sum_i32(c);
        if (lane == 0) shm.swv[it & 3][wid] = c;
        __syncthreads();
        int tot = shm.swv[it & 3][0] + shm.swv[it & 3][1]
                + shm.swv[it & 3][2] + shm.swv[it & 3][3];
        if (tot >= NS) { hi = piv; cHi = tot; }
        else           { lo = piv + 1; cLo = tot; }
        ++it;
    }

    const int clt = cLo;           // |{key < lo}| < NS  (uniform)
    const int R = NS - cLo;        // to take from the band, >= 1

    // compact A = {key < lo}
#pragma unroll
    for (int j = 0; j < NPL; ++j) {
        bool s = ok[j] < lo;
        unsigned long long mk = __ballot(s);
        int n = __popcll(mk);
        if (n) {
            int wb = 0;
            if (lane == 0) wb = atomicAdd(&shm.scnt, n);
            wb = __shfl(wb, 0, WAVE);
            if (s) shm.sel[wb + __popcll(mk & lmask)] = j * 256 + tid;
        }
    }
    // compact band B = {lo <= key <= hi}
#pragma unroll
    for (int j = 0; j < NPL; ++j) {
        bool s = (ok[j] >= lo) && (ok[j] <= hi);
        unsigned long long mk = __ballot(s);
        int n = __popcll(mk);
        if (n) {
            int wb = 0;
            if (lane == 0) wb = atomicAdd(&shm.bcnt, n);
            wb = __shfl(wb, 0, WAVE);
            int slot = wb + __popcll(mk & lmask);
            if (s && slot < 64)
                shm.cbuf[slot] =
                    ((unsigned long long)ok[j] << 32) | (unsigned)(j * 256 + tid);
        }
    }
    __syncthreads();
    int Bcnt = shm.bcnt;           // uniform

    if (Bcnt <= 64) {
        if (wid == 0) {
            unsigned long long p = (lane < Bcnt) ? shm.cbuf[lane] : ~0ull;
            p = bitonic_sort64(p, lane);
            if (lane < R) shm.sel[clt + lane] = (int)(unsigned)p;
        }
        __syncthreads();
    } else {
        // rare: massive key ties — exact R-round block-wide u64 min
        unsigned consumed = 0u;    // NPL <= 16 bits
        for (int r = 0; r < R; ++r) {
            unsigned long long mv = ~0ull;
#pragma unroll
            for (int j = 0; j < NPL; ++j) {
                bool s = (ok[j] >= lo) && (ok[j] <= hi) && !((consumed >> j) & 1u);
                unsigned long long p =
                    ((unsigned long long)ok[j] << 32) | (unsigned)(j * 256 + tid);
                mv = (s && p < mv) ? p : mv;
            }
            mv = wave_min_u64(mv);
            if (lane == 0) shm.mw[wid] = mv;
            __syncthreads();
            unsigned long long m0 = shm.mw[0], m1 = shm.mw[1];
            unsigned long long m2 = shm.mw[2], m3 = shm.mw[3];
            unsigned long long ta = (m0 < m1) ? m0 : m1;
            unsigned long long tb = (m2 < m3) ? m2 : m3;
            unsigned long long t = (ta < tb) ? ta : tb;
#pragma unroll
            for (int j = 0; j < NPL; ++j) {
                unsigned long long p =
                    ((unsigned long long)ok[j] << 32) | (unsigned)(j * 256 + tid);
                if (p == t) consumed |= 1u << j;
            }
            if (tid == 0) shm.sel[clt + r] = (int)(unsigned)t;
            __syncthreads();
        }
    }
}

// ---------------------------------------------------------------------------
template <int NQ, int K>
__device__ __forceinline__ void knn_level(
    const float* __restrict__ qc, const float4* __restrict__ pk0,
    const int* __restrict__ rl, int* __restrict__ out,
    int q, SelShm& shm, int tid)
{
    int b = q / NQ, qi = q - b * NQ;
    const float* qp = qc + ((long)b * NQ + qi) * 3;
    float qx = qp[0], qy = qp[1], qz = qp[2];
    float nq = qx * qx + qy * qy + qz * qz;
    block_topNS<4096, K>(pk0 + (long)b * 4096, qx, qy, qz, nq, shm, tid);
    if ((tid >> 6) == 0) {
        int lane = tid & 63;
        int lb = (lane < K) ? rl[(long)b * 4096 + shm.sel[lane]] : -1;
        int cnt = 0;
#pragma unroll
        for (int k = 0; k < K; ++k) {
            int lk = __shfl(lb, k, WAVE);
            cnt += (lk == lane) ? 1 : 0;
        }
        int key = (lane < NC) ? ((cnt << 8) | (255 - lane)) : 0;
#pragma unroll
        for (int off = 32; off >= 1; off >>= 1) {
            int o = __shfl_xor(key, off, WAVE);
            key = (o > key) ? o : key;
        }
        if (lane == 0) out[(long)b * NQ + qi] = 255 - (key & 255);
    }
}

template <int NI, int NS>
__device__ __forceinline__ void boundary_epilogue(
    const float* __restrict__ feat, const int* __restrict__ lbl,
    double* __restrict__ pos, double* __restrict__ neg, int* __restrict__ anyf,
    int b, int qi, int lane, int nb)
{
    int center = lbl[(long)b * NI + qi];
    bool m = false;
    float dj = -INFINITY;
    if (lane < NS) {
        m = (lbl[(long)b * NI + nb] == center);
        const float4* fq = (const float4*)(feat + ((long)b * NI + qi) * 32);
        const float4* fn = (const float4*)(feat + ((long)b * NI + nb) * 32);
        float s = 0.f;
#pragma unroll
        for (int d = 0; d < 8; ++d) {
            float4 a = fq[d], c = fn[d];
            float d0 = a.x - c.x, d1 = a.y - c.y;
            float d2 = a.z - c.z, d3 = a.w - c.w;
            s += d0 * d0 + d1 * d1 + d2 * d2 + d3 * d3;
        }
        dj = -sqrtf(s + 1e-6f);
    }
    unsigned long long mb = __ballot(m);
    int cnt = __popcll(mb);
    float mxv = wave_max_f32(dj);          // lanes >= NS hold -inf
    float ej = 0.f, pj = 0.f;
    if (lane < NS) {
        ej = expf(dj - mxv);               // TEMPERATURE == 1
        pj = m ? ej : 0.f;
    }
    float se = wave_sum_f32(ej);
    float sp = wave_sum_f32(pj);
    bool pm = (cnt > 0) && (cnt < NS);
    if (pm && lane == 0) {
        atomicAdd(pos, (double)sp);
        atomicAdd(neg, (double)se);
        *anyf = 1;
    }
}

template <int NI, int NS>
__device__ __forceinline__ void boundary_level(
    const float4* __restrict__ pk, const float* __restrict__ coord,
    const float* __restrict__ feat, const int* __restrict__ lbl,
    double* __restrict__ pos, double* __restrict__ neg, int* __restrict__ anyf,
    int q, SelShm& shm, int tid)
{
    int b = q / NI, qi = q - b * NI;
    const float* qp = coord + ((long)b * NI + qi) * 3;
    float qx = qp[0], qy = qp[1], qz = qp[2];
    float nq = qx * qx + qy * qy + qz * qz;
    block_topNS<NI, NS>(pk + (long)b * NI, qx, qy, qz, nq, shm, tid);
    if ((tid >> 6) == 0)
        boundary_epilogue<NI, NS>(feat, lbl, pos, neg, anyf,
                                  b, qi, tid & 63, shm.sel[tid & 63]);
}

// small levels (NI <= 64): wave 0 direct bitonic, no LDS/barriers
template <int NI, int NS>
__device__ __forceinline__ void small_boundary_level(
    const float4* __restrict__ pk, const float* __restrict__ coord,
    const float* __restrict__ feat, const int* __restrict__ lbl,
    double* __restrict__ pos, double* __restrict__ neg, int* __restrict__ anyf,
    int q, int tid)
{
    if (tid >= 64) return;
    int lane = tid;
    int b = q / NI, qi = q - b * NI;
    const float* qp = coord + ((long)b * NI + qi) * 3;
    float qx = qp[0], qy = qp[1], qz = qp[2];
    float nq = qx * qx + qy * qy + qz * qz;
    unsigned long long p = ~0ull;
    if (lane < NI) {
        float4 P = pk[(long)b * NI + lane];
        float dot = qx * P.x + qy * P.y + qz * P.z;
        unsigned o = f32_ord(-2.0f * dot + nq + P.w);
        p = ((unsigned long long)o << 32) | (unsigned)lane;
    }
    unsigned long long h = bitonic_sort64(p, lane);
    boundary_epilogue<NI, NS>(feat, lbl, pos, neg, anyf,
                              b, qi, lane, (int)(unsigned)h);
}

// ---------------------------------------------------------------------------
__global__ __launch_bounds__(256) void pack_kernel(
    const float* __restrict__ c0, const float* __restrict__ c1,
    const float* __restrict__ c2, const float* __restrict__ c3,
    const float* __restrict__ c4,
    float4* __restrict__ p0, float4* __restrict__ p1,
    float4* __restrict__ p2, float4* __restrict__ p3,
    float4* __restrict__ p4,
    double* __restrict__ posA, double* __restrict__ negA,
    int* __restrict__ anyA, int B)
{
    int idx = blockIdx.x * 256 + threadIdx.x;
    if (idx < 5) { posA[idx] = 0.0; negA[idx] = 0.0; anyA[idx] = 0; }
    int s0 = B * 4096, s1 = s0 + B * 1024, s2 = s1 + B * 256;
    int s3 = s2 + B * 64, s4 = s3 + B * 16;
    const float* src; float4* dst; int i;
    if (idx < s0)      { src = c0; dst = p0; i = idx; }
    else if (idx < s1) { src = c1; dst = p1; i = idx - s0; }
    else if (idx < s2) { src = c2; dst = p2; i = idx - s1; }
    else if (idx < s3) { src = c3; dst = p3; i = idx - s2; }
    else if (idx < s4) { src = c4; dst = p4; i = idx - s3; }
    else return;
    float x = src[3 * i], y = src[3 * i + 1], z = src[3 * i + 2];
    dst[i] = make_float4(x, y, z, x * x + y * y + z * z);   // nr expr identical
}

__global__ __launch_bounds__(256) void knn_fused(
    const float* __restrict__ c1, const float* __restrict__ c2,
    const float* __restrict__ c3, const float* __restrict__ c4,
    const float4* __restrict__ pk0, const int* __restrict__ labels,
    int* __restrict__ lbl1, int* __restrict__ lbl2,
    int* __restrict__ lbl3, int* __restrict__ lbl4, int B)
{
    __shared__ SelShm shm;
    int q = blockIdx.x, tid = threadIdx.x;
    int n1 = B * 1024, n2 = n1 + B * 256, n3 = n2 + B * 64, n4 = n3 + B * 16;
    if (q < n1)      knn_level<1024, 4>(c1, pk0, labels, lbl1, q,      shm, tid);
    else if (q < n2) knn_level<256,  8>(c2, pk0, labels, lbl2, q - n1, shm, tid);
    else if (q < n3) knn_level<64,  12>(c3, pk0, labels, lbl3, q - n2, shm, tid);
    else if (q < n4) knn_level<16,  16>(c4, pk0, labels, lbl4, q - n3, shm, tid);
}

__global__ __launch_bounds__(256) void boundary_fused(
    const float4* __restrict__ p0, const float4* __restrict__ p1,
    const float4* __restrict__ p2, const float4* __restrict__ p3,
    const float4* __restrict__ p4,
    const float* __restrict__ c0, const float* __restrict__ c1,
    const float* __restrict__ c2, const float* __restrict__ c3,
    const float* __restrict__ c4,
    const float* __restrict__ f0, const float* __restrict__ f1,
    const float* __restrict__ f2, const float* __restrict__ f3,
    const float* __restrict__ f4,
    const int* __restrict__ labels, const int* __restrict__ lbl1,
    const int* __restrict__ lbl2, const int* __restrict__ lbl3,
    const int* __restrict__ lbl4,
    double* __restrict__ posA, double* __restrict__ negA,
    int* __restrict__ anyA, int B)
{
    __shared__ SelShm shm;
    int q = blockIdx.x, tid = threadIdx.x;
    int m0 = B * 4096, m1 = m0 + B * 1024, m2 = m1 + B * 256;
    int m3 = m2 + B * 64, m4 = m3 + B * 16;
    if (q < m0)
        boundary_level<4096, 64>(p0, c0, f0, labels, posA+0, negA+0, anyA+0, q,      shm, tid);
    else if (q < m1)
        boundary_level<1024, 32>(p1, c1, f1, lbl1,   posA+1, negA+1, anyA+1, q - m0, shm, tid);
    else if (q < m2)
        boundary_level<256,  16>(p2, c2, f2, lbl2,   posA+2, negA+2, anyA+2, q - m1, shm, tid);
    else if (q < m3)
        small_boundary_level<64, 8>(p3, c3, f3, lbl3, posA+3, negA+3, anyA+3, q - m2, tid);
    else if (q < m4)
        small_boundary_level<16, 4>(p4, c4, f4, lbl4, posA+4, negA+4, anyA+4, q - m3, tid);
}

__global__ void finalize_kernel(const double* __restrict__ pos,
                                const double* __restrict__ neg,
                                const int* __restrict__ anyf,
                                float* __restrict__ out) {
    if (threadIdx.x == 0 && blockIdx.x == 0) {
        float loss = 0.f;
        for (int i = 0; i < 5; ++i) {
            if (anyf[i]) {
                float p = (float)pos[i];
                float n = (float)neg[i];
                loss += -logf(p / (n + 1e-6f));
            }
        }
        out[0] = loss;
    }
}

extern "C" void kernel_launch(void* const* d_in, const int* in_sizes, int n_in,
                              void* d_out, int out_size, void* d_ws, size_t ws_size,
                              hipStream_t stream) {
    (void)out_size; (void)ws_size;
    const int* labels = (const int*)d_in[0];
    const float* coord[5];
    const float* feat[5];
    bool interleaved = (n_in >= 3 && in_sizes[2] == 2 * 4096 * 32);
    if (interleaved) {
        for (int i = 0; i < 5; ++i) {
            coord[i] = (const float*)d_in[1 + 2 * i];
            feat[i]  = (const float*)d_in[2 + 2 * i];
        }
    } else {
        for (int i = 0; i < 5; ++i) {
            coord[i] = (const float*)d_in[1 + i];
            feat[i]  = (const float*)d_in[6 + i];
        }
    }
    int B = in_sizes[0] / 4096;   // = 2

    char* ws = (char*)d_ws;
    double* posA = (double*)ws;                       // 5 doubles @0
    double* negA = posA + 5;                          // @40
    int* anyA = (int*)(negA + 5);                     // @80, 8 ints
    int* lbl1 = anyA + 8;                             // @112
    int* lbl2 = lbl1 + B * 1024;
    int* lbl3 = lbl2 + B * 256;
    int* lbl4 = lbl3 + B * 64;
    size_t off = 112 + (size_t)B * (1024 + 256 + 64 + 16) * 4;
    off = (off + 15) & ~(size_t)15;                   // 16B align for float4
    float4* pk0 = (float4*)(ws + off); off += (size_t)B * 4096 * 16;
    float4* pk1 = (float4*)(ws + off); off += (size_t)B * 1024 * 16;
    float4* pk2 = (float4*)(ws + off); off += (size_t)B * 256 * 16;
    float4* pk3 = (float4*)(ws + off); off += (size_t)B * 64 * 16;
    float4* pk4 = (float4*)(ws + off);

    int tot = B * (4096 + 1024 + 256 + 64 + 16);
    hipLaunchKernelGGL(pack_kernel, dim3((tot + 255) / 256), dim3(256), 0, stream,
                       coord[0], coord[1], coord[2], coord[3], coord[4],
                       pk0, pk1, pk2, pk3, pk4, posA, negA, anyA, B);

    int n4 = B * (1024 + 256 + 64 + 16);
    hipLaunchKernelGGL(knn_fused, dim3(n4), dim3(256), 0, stream,
                       coord[1], coord[2], coord[3], coord[4],
                       pk0, labels, lbl1, lbl2, lbl3, lbl4, B);

    hipLaunchKernelGGL(boundary_fused, dim3(tot), dim3(256), 0, stream,
                       pk0, pk1, pk2, pk3, pk4,
                       coord[0], coord[1], coord[2], coord[3], coord[4],
                       feat[0], feat[1], feat[2], feat[3], feat[4],
                       labels, lbl1, lbl2, lbl3, lbl4,
                       posA, negA, anyA, B);

    hipLaunchKernelGGL(finalize_kernel, dim3(1), dim3(1), 0, stream,
                       posA, negA, anyA, (float*)d_out);
}